// Round 3
// baseline (365.445 us; speedup 1.0000x reference)
//
#include <hip/hip_runtime.h>

typedef unsigned short u16;
typedef __attribute__((ext_vector_type(8))) short bf16x8;
typedef __attribute__((ext_vector_type(4))) float f32x4;

#define MFMA(a, b, c) __builtin_amdgcn_mfma_f32_16x16x32_bf16(a, b, c, 0, 0, 0)
#define EXP2(x) exp2f(x)

// async global->LDS, 16B per lane; lds ptr must be wave-uniform base.
#define ASYNC16(g, l)                                                      \
  __builtin_amdgcn_global_load_lds(                                        \
      (const __attribute__((address_space(1))) void*)(g),                  \
      (__attribute__((address_space(3))) void*)(l), 16, 0, 0)

__device__ __forceinline__ u16 f2bf(float x) {
  union { float f; unsigned u; } v; v.f = x;
  unsigned r = (v.u + 0x7fffu + ((v.u >> 16) & 1u)) >> 16;
  return (u16)r;
}

// pack two f32 -> bf16x2 (round-half-up): [hi16(a+0x8000), hi16(b+0x8000)]
__device__ __forceinline__ unsigned pack_bf2(float a, float b) {
  unsigned ua = __float_as_uint(a) + 0x8000u;
  unsigned ub = __float_as_uint(b) + 0x8000u;
  return __builtin_amdgcn_perm(ub, ua, 0x07060302u);  // D=[ua.hi16, ub.hi16]
}

// ---------------- transpose + fp32->bf16 (w_in, w_out) ----------------
__global__ void transpose_to_bf16(const float* __restrict__ in, u16* __restrict__ out,
                                  int R, int C) {
  __shared__ float tile[32][33];
  int c0 = blockIdx.x * 32, r0 = blockIdx.y * 32;
  int tx = threadIdx.x, ty = threadIdx.y;  // 32 x 8
#pragma unroll
  for (int i = 0; i < 32; i += 8)
    tile[ty + i][tx] = in[(size_t)(r0 + ty + i) * C + c0 + tx];
  __syncthreads();
#pragma unroll
  for (int i = 0; i < 32; i += 8)
    out[(size_t)(c0 + ty + i) * R + r0 + tx] = f2bf(tile[tx][ty + i]);
}

// ---------------- fp32 -> bf16 (x) ----------------
__global__ void f32_to_bf16_vec(const float4* __restrict__ in, uint2* __restrict__ out) {
  int idx = blockIdx.x * 256 + threadIdx.x;
  float4 v = in[idx];
  out[idx] = make_uint2(pack_bf2(v.x, v.y), pack_bf2(v.z, v.w));
}

// ---------------- GEMM (m97 structure): C = A * Bt^T + bias ----------------
// Unpadded LDS (stride BK) as required by global_load_lds lane mapping.
#define BM 128
#define BN 128
#define BK 64

template <int OUT_F32>
__global__ __launch_bounds__(256, 2) void gemm_bt(const u16* __restrict__ A,
                                                  const u16* __restrict__ Bt,
                                                  const float* __restrict__ bias,
                                                  void* __restrict__ Cout,
                                                  int M, int N, int K, int ldc,
                                                  int sc_lo, int sc_hi, float qs) {
  __shared__ __align__(16) u16 As[BM * BK];
  __shared__ __align__(16) u16 Bs[BN * BK];
  int bn = blockIdx.x * BN, bm = blockIdx.y * BM;
  int tid = threadIdx.x;
  int wave = tid >> 6, lane = tid & 63;
  int quad = lane >> 4, l16 = lane & 15;
  int wm = (wave >> 1) * 64, wn = (wave & 1) * 64;

  f32x4 acc[4][4] = {};

  // staging: lane l covers row (wave*8 + l/8), cols (l%8)*8..+8 of each 32-row chunk
  int lrow = lane >> 3, lcol = (lane & 7) * 8;
  const u16* gA = A + (size_t)(bm + wave * 8 + lrow) * K + lcol;
  const u16* gB = Bt + (size_t)(bn + wave * 8 + lrow) * K + lcol;
  u16* lA = &As[wave * 8 * BK];  // wave-uniform
  u16* lB = &Bs[wave * 8 * BK];

  for (int k0 = 0; k0 < K; k0 += BK) {
#pragma unroll
    for (int p = 0; p < 4; ++p) {
      ASYNC16(gA + (size_t)p * 32 * K, lA + p * 32 * BK);
      ASYNC16(gB + (size_t)p * 32 * K, lB + p * 32 * BK);
    }
    gA += BK;
    gB += BK;
    __syncthreads();
#pragma unroll
    for (int kk = 0; kk < BK; kk += 32) {
      bf16x8 af[4], bfr[4];
#pragma unroll
      for (int i = 0; i < 4; ++i)
        af[i] = *(const bf16x8*)&As[(wm + 16 * i + l16) * BK + kk + quad * 8];
#pragma unroll
      for (int j = 0; j < 4; ++j)
        bfr[j] = *(const bf16x8*)&Bs[(wn + 16 * j + l16) * BK + kk + quad * 8];
#pragma unroll
      for (int i = 0; i < 4; ++i)
#pragma unroll
        for (int j = 0; j < 4; ++j)
          acc[i][j] = MFMA(af[i], bfr[j], acc[i][j]);
    }
    __syncthreads();
  }

#pragma unroll
  for (int i = 0; i < 4; ++i) {
#pragma unroll
    for (int j = 0; j < 4; ++j) {
      int gn = bn + wn + 16 * j + l16;
      float bv = bias[gn];
      float sc = (gn >= sc_lo && gn < sc_hi) ? qs : 1.0f;
#pragma unroll
      for (int r = 0; r < 4; ++r) {
        int gm = bm + wm + 16 * i + quad * 4 + r;
        float v = (acc[i][j][r] + bv) * sc;
        if (OUT_F32)
          ((float*)Cout)[(size_t)gm * ldc + gn] = v;
        else
          ((u16*)Cout)[(size_t)gm * ldc + gn] = f2bf(v);
      }
    }
  }
}

// ---------------- flash attention v3 ----------------
// Register-prefetched K/V staging; perm-packed P; ones-MFMA row sum; no max shift.
#define SEQ 2048
#define ROWS3 3072
#define ABN 64
#define LDK 72
#define LDV 66
#define LDP 68

__global__ __launch_bounds__(256, 3) void attn_kernel(const u16* __restrict__ kqv,
                                                      u16* __restrict__ out) {
  int bh = blockIdx.y;
  int b = bh >> 4, h = bh & 15;
  int tid = threadIdx.x, wave = tid >> 6, lane = tid & 63;
  int quad = lane >> 4, l16 = lane & 15;

  __shared__ __align__(16) u16 Ks[ABN * LDK];
  __shared__ __align__(16) u16 Vt[64 * LDV];
  __shared__ __align__(16) u16 Ps[4][32 * LDP];

  const u16* base = kqv + (size_t)b * SEQ * ROWS3;
  int hcol = h * 64;

  bf16x8 qf[2][2];
#pragma unroll
  for (int t = 0; t < 2; ++t) {
    int s = blockIdx.x * 128 + wave * 32 + t * 16 + l16;
    const u16* qrow = base + (size_t)s * ROWS3 + 1024 + hcol;  // Q_OFF=1024
    qf[t][0] = *(const bf16x8*)(qrow + quad * 8);
    qf[t][1] = *(const bf16x8*)(qrow + 32 + quad * 8);
  }

  bf16x8 ones;
#pragma unroll
  for (int i = 0; i < 8; ++i) ones[i] = (short)0x3F80;

  f32x4 o[2][4] = {};
  f32x4 ol[2] = {};

  int srow = tid >> 3;        // 0..31
  int scol = (tid & 7) * 8;   // 0..56
  u16* pw = &Ps[wave][0];

  // prefetch tile 0 into registers
  uint4 kreg[2], vreg[2];
#pragma unroll
  for (int p2 = 0; p2 < 2; ++p2) {
    const u16* row = base + (size_t)(p2 * 32 + srow) * ROWS3 + hcol;
    kreg[p2] = *(const uint4*)(row + scol);
    vreg[p2] = *(const uint4*)(row + 2048 + scol);
  }

  for (int t0 = 0; t0 < SEQ; t0 += ABN) {
    __syncthreads();
#pragma unroll
    for (int p2 = 0; p2 < 2; ++p2) {
      int k = p2 * 32 + srow;
      *(uint4*)&Ks[k * LDK + scol] = kreg[p2];
      u16* vp = (u16*)&vreg[p2];
      int col = 4 * (k & 15) + (k >> 4);  // permuted contraction position
#pragma unroll
      for (int i = 0; i < 8; ++i) Vt[(scol + i) * LDV + col] = vp[i];
    }
    __syncthreads();

    // prefetch next tile while this tile computes
    if (t0 + ABN < SEQ) {
#pragma unroll
      for (int p2 = 0; p2 < 2; ++p2) {
        const u16* row = base + (size_t)(t0 + ABN + p2 * 32 + srow) * ROWS3 + hcol;
        kreg[p2] = *(const uint4*)(row + scol);
        vreg[p2] = *(const uint4*)(row + 2048 + scol);
      }
    }

    bf16x8 kf[4][2];
#pragma unroll
    for (int j = 0; j < 4; ++j) {
      kf[j][0] = *(const bf16x8*)&Ks[(16 * j + l16) * LDK + quad * 8];
      kf[j][1] = *(const bf16x8*)&Ks[(16 * j + l16) * LDK + 32 + quad * 8];
    }

    f32x4 s[2][4] = {};
#pragma unroll
    for (int t = 0; t < 2; ++t)
#pragma unroll
      for (int j = 0; j < 4; ++j) {
        s[t][j] = MFMA(qf[t][0], kf[j][0], s[t][j]);
        s[t][j] = MFMA(qf[t][1], kf[j][1], s[t][j]);
      }

#pragma unroll
    for (int t = 0; t < 2; ++t)
#pragma unroll
      for (int r = 0; r < 4; ++r) {
        float p0 = EXP2(s[t][0][r]);
        float p1 = EXP2(s[t][1][r]);
        float p2 = EXP2(s[t][2][r]);
        float p3 = EXP2(s[t][3][r]);
        uint2 pk;
        pk.x = pack_bf2(p0, p1);
        pk.y = pack_bf2(p2, p3);
        *(uint2*)&pw[(t * 16 + quad * 4 + r) * LDP + 4 * l16] = pk;
      }

    bf16x8 vf[4][2];
#pragma unroll
    for (int d = 0; d < 4; ++d) {
      vf[d][0] = *(const bf16x8*)&Vt[(16 * d + l16) * LDV + quad * 8];
      vf[d][1] = *(const bf16x8*)&Vt[(16 * d + l16) * LDV + 32 + quad * 8];
    }

#pragma unroll
    for (int t = 0; t < 2; ++t) {
      bf16x8 pa0 = *(const bf16x8*)&pw[(t * 16 + l16) * LDP + quad * 8];
      bf16x8 pa1 = *(const bf16x8*)&pw[(t * 16 + l16) * LDP + 32 + quad * 8];
#pragma unroll
      for (int d = 0; d < 4; ++d) {
        o[t][d] = MFMA(pa0, vf[d][0], o[t][d]);
        o[t][d] = MFMA(pa1, vf[d][1], o[t][d]);
      }
      ol[t] = MFMA(pa0, ones, ol[t]);
      ol[t] = MFMA(pa1, ones, ol[t]);
    }
  }

#pragma unroll
  for (int t = 0; t < 2; ++t)
#pragma unroll
    for (int r = 0; r < 4; ++r) {
      float inv = 1.0f / ol[t][r];
      int s = blockIdx.x * 128 + wave * 32 + t * 16 + quad * 4 + r;
      u16* orow = out + (size_t)(b * SEQ + s) * 1024 + hcol;
#pragma unroll
      for (int d = 0; d < 4; ++d) orow[16 * d + l16] = f2bf(o[t][d][r] * inv);
    }
}

extern "C" void kernel_launch(void* const* d_in, const int* in_sizes, int n_in,
                              void* d_out, int out_size, void* d_ws, size_t ws_size,
                              hipStream_t stream) {
  const float* x     = (const float*)d_in[0];
  const float* w_in  = (const float*)d_in[1];
  const float* b_in  = (const float*)d_in[2];
  const float* w_out = (const float*)d_in[3];
  const float* b_out = (const float*)d_in[4];
  float* outp = (float*)d_out;

  char* p = (char*)d_ws;
  u16* wT_in  = (u16*)p; p += (size_t)3072 * 1024 * 2;
  u16* wT_out = (u16*)p; p += (size_t)1024 * 1024 * 2;
  u16* xb     = (u16*)p; p += (size_t)8192 * 1024 * 2;
  u16* kqv    = (u16*)p; p += (size_t)8192 * 3072 * 2;
  u16* attn   = (u16*)p;

  transpose_to_bf16<<<dim3(3072 / 32, 1024 / 32), dim3(32, 8), 0, stream>>>(w_in, wT_in, 1024, 3072);
  transpose_to_bf16<<<dim3(1024 / 32, 1024 / 32), dim3(32, 8), 0, stream>>>(w_out, wT_out, 1024, 1024);
  f32_to_bf16_vec<<<dim3(8192), dim3(256), 0, stream>>>((const float4*)x, (uint2*)xb);

  const float QSCALE = 0.125f * 1.44269504088896f;
  gemm_bt<0><<<dim3(3072 / BN, 8192 / BM), 256, 0, stream>>>(
      xb, wT_in, b_in, (void*)kqv, 8192, 3072, 1024, 3072, 1024, 2048, QSCALE);

  attn_kernel<<<dim3(SEQ / 128, 64), 256, 0, stream>>>(kqv, attn);

  gemm_bt<1><<<dim3(1024 / BN, 8192 / BM), 256, 0, stream>>>(
      attn, wT_out, b_out, (void*)outp, 8192, 1024, 1024, 1024, 0, 0, 1.0f);
}